// Round 7
// baseline (321.588 us; speedup 1.0000x reference)
//
#include <hip/hip_runtime.h>
#include <math.h>

#define B_TOTAL 16384
#define T_STEPS 20
#define NGRP    1024            // B_TOTAL/16 batch groups per sensor

typedef __attribute__((ext_vector_type(8))) __bf16 bf16x8;
typedef __attribute__((ext_vector_type(4))) float f32x4;

// ---------------------------------------------------------------------------
// Truncation-based Dekker split: hi = top-16-bits of x, lo = top-16 of (x-hi).
__device__ __forceinline__ __bf16 bf16_bits(unsigned short s) {
    __bf16 r; __builtin_memcpy(&r, &s, 2); return r;
}
__device__ __forceinline__ void split_trunc(float x, __bf16& hi, __bf16& lo) {
    unsigned u = __float_as_uint(x);
    hi = bf16_bits((unsigned short)(u >> 16));
    float l = x - __uint_as_float(u & 0xFFFF0000u);
    lo = bf16_bits((unsigned short)(__float_as_uint(l) >> 16));
}

// ---------------------------------------------------------------------------
// Fused 5-layer LSTM via bf16 MFMA, hi/lo compensated.
// Activations use ONE rcp per unit for the 4 gate denominators (prefix/suffix
// product inverse) + one shared rcp for the two cell-tanh denominators:
// 13 transcendental ops/thread-step instead of 20 (trans issue = 4 lanes/cyc).
// Exp args clamped (<=17 gates, <=30 cell) so products stay finite.
__global__ __launch_bounds__(256, 4)
void lstm5_mfma(const float* __restrict__ accel, const float* __restrict__ gyro,
                const float* __restrict__ aWih0, const float* __restrict__ aWihR,
                const float* __restrict__ aWhh,  const float* __restrict__ aBih,
                const float* __restrict__ aBhh,
                const float* __restrict__ gWih0, const float* __restrict__ gWihR,
                const float* __restrict__ gWhh,  const float* __restrict__ gBih,
                const float* __restrict__ gBhh,
                const float* __restrict__ fc1_w,
                __bf16* __restrict__ w1ah, __bf16* __restrict__ w1al,
                __bf16* __restrict__ Xhi, __bf16* __restrict__ Xlo) {
    const int tid  = threadIdx.x;
    const int w    = tid >> 6;        // wave 0..3
    const int lane = tid & 63;
    const int e    = lane & 15;       // elem (B-frag col / C col)
    const int quad = lane >> 4;       // 0..3
    const int sensor = blockIdx.y;
    const int bbase  = blockIdx.x * 16;

    // ---- merged w1_prep preamble (80 of 2048 blocks; saves a launch) ----
    if (sensor == 0 && blockIdx.x < 80) {
        int idx = blockIdx.x * 256 + tid;            // < 20480
        int plane = idx & 63;
        int ks    = (idx >> 6) % 40;
        int mt    = idx / (64 * 40);
        int row   = mt * 16 + (plane & 15);
        int col0  = ks * 32 + (plane >> 4) * 8;
        const float* src = fc1_w + row * 1280 + col0;
#pragma unroll
        for (int j = 0; j < 8; ++j) {
            __bf16 h_, l_;
            split_trunc(src[j], h_, l_);
            w1ah[(size_t)idx * 8 + j] = h_;
            w1al[(size_t)idx * 8 + j] = l_;
        }
    }

    const float* xin  = sensor ? gyro  : accel;
    const float* Wih0 = sensor ? gWih0 : aWih0;
    const float* WihR = sensor ? gWihR : aWihR;
    const float* Whh  = sensor ? gWhh  : aWhh;
    const float* Bih  = sensor ? gBih  : aBih;
    const float* Bhh  = sensor ? gBhh  : aBhh;

    __shared__ __align__(16) __bf16 shi[20 * 512];    // [t][chunk][e][j]
    __shared__ __align__(16) __bf16 slo[20 * 512];

    const int ug0 = w * 8 + quad;        // tile 0 unit
    const int ug1 = w * 8 + 4 + quad;    // tile 1 unit

    const int m_row   = lane & 15;
    const int orow_t0 = (m_row & 3) * 32 + (w * 8 + (m_row >> 2));
    const int orow_t1 = (m_row & 3) * 32 + (w * 8 + 4 + (m_row >> 2));

    bf16x8 wih_h0, wih_l0, wih_h1, wih_l1;
    bf16x8 whh_h0, whh_l0, whh_h1, whh_l1;
    f32x4  bias0v, bias1v;
    float  c0 = 0.f, c1 = 0.f;

#define LOAD_FRAG(Wsrc, orow, fh, fl)                         \
    {                                                         \
        const float* p_ = (Wsrc) + (orow) * 32 + quad * 8;    \
        _Pragma("unroll")                                     \
        for (int jj = 0; jj < 8; ++jj) {                      \
            __bf16 h_, l_;                                    \
            split_trunc(p_[jj], h_, l_);                      \
            (fh)[jj] = h_;  (fl)[jj] = l_;                    \
        }                                                     \
    }

#define LOAD_BIAS(l)                                                        \
    {                                                                       \
        _Pragma("unroll")                                                   \
        for (int r = 0; r < 4; ++r) {                                       \
            bias0v[r] = Bih[(l) * 128 + r * 32 + ug0] + Bhh[(l) * 128 + r * 32 + ug0]; \
            bias1v[r] = Bih[(l) * 128 + r * 32 + ug1] + Bhh[(l) * 128 + r * 32 + ug1]; \
        }                                                                   \
    }

    // gates via single-rcp 4-way inverse per unit; cell tanh pair shares 1 rcp
#define ACT_STORE(t)                                                        \
    {                                                                       \
        float d1 = 1.f + __expf(fminf(-acc0[0], 17.f));                     \
        float d2 = 1.f + __expf(fminf(-acc0[1], 17.f));                     \
        float d3 = 1.f + __expf(fminf(2.f * acc0[2], 17.f));                \
        float d4 = 1.f + __expf(fminf(-acc0[3], 17.f));                     \
        float p2 = d1 * d2, p3 = p2 * d3, P = p3 * d4;                      \
        float s3 = d3 * d4, s2 = d2 * s3;                                   \
        float R  = __builtin_amdgcn_rcpf(P);                                \
        float i0 = R * s2;                                                  \
        float f0 = R * d1 * s3;                                             \
        float g0 = fmaf(-2.f, R * p2 * d4, 1.f);                            \
        float o0 = R * p3;                                                  \
        c0 = fmaf(f0, c0, i0 * g0);                                         \
        float e1 = 1.f + __expf(fminf(-acc1[0], 17.f));                     \
        float e2 = 1.f + __expf(fminf(-acc1[1], 17.f));                     \
        float e3 = 1.f + __expf(fminf(2.f * acc1[2], 17.f));                \
        float e4 = 1.f + __expf(fminf(-acc1[3], 17.f));                     \
        float q2 = e1 * e2, q3 = q2 * e3, Q = q3 * e4;                      \
        float u3 = e3 * e4, u2 = e2 * u3;                                   \
        float S  = __builtin_amdgcn_rcpf(Q);                                \
        float i1 = S * u2;                                                  \
        float f1 = S * e1 * u3;                                             \
        float g1 = fmaf(-2.f, S * q2 * e4, 1.f);                            \
        float o1 = S * q3;                                                  \
        c1 = fmaf(f1, c1, i1 * g1);                                         \
        float d9 = 1.f + __expf(fminf(2.f * c0, 30.f));                     \
        float da = 1.f + __expf(fminf(2.f * c1, 30.f));                     \
        float R2 = __builtin_amdgcn_rcpf(d9 * da);                          \
        float h0 = fmaf(-2.f, o0 * (R2 * da), o0);                          \
        float h1 = fmaf(-2.f, o1 * (R2 * d9), o1);                          \
        __syncthreads();  /* all waves done reading shi/slo[t] */           \
        int i0x = (t) * 512 + w * 128 + e * 8 + quad;                       \
        int i1x = i0x + 4;                                                  \
        __bf16 hh_, ll_;                                                    \
        split_trunc(h0, hh_, ll_);  shi[i0x] = hh_;  slo[i0x] = ll_;        \
        split_trunc(h1, hh_, ll_);  shi[i1x] = hh_;  slo[i1x] = ll_;        \
        __syncthreads();  /* writes visible before next step's reads */     \
    }

    // ================= layer 0 (ih is K=3, done in VALU) =================
    {
        LOAD_FRAG(Whh, orow_t0, whh_h0, whh_l0);
        LOAD_FRAG(Whh, orow_t1, whh_h1, whh_l1);
        LOAD_BIAS(0);
        float w0reg[2][4][3];
#pragma unroll
        for (int r = 0; r < 4; ++r)
#pragma unroll
            for (int k = 0; k < 3; ++k) {
                w0reg[0][r][k] = Wih0[(r * 32 + ug0) * 3 + k];
                w0reg[1][r][k] = Wih0[(r * 32 + ug1) * 3 + k];
            }
        const float* xrow = xin + (size_t)(bbase + e) * (T_STEPS * 3);

        for (int t = 0; t < T_STEPS; ++t) {
            float x0 = xrow[t * 3 + 0];
            float x1 = xrow[t * 3 + 1];
            float x2 = xrow[t * 3 + 2];
            f32x4 acc0 = bias0v;
            f32x4 acc1 = bias1v;
#pragma unroll
            for (int r = 0; r < 4; ++r) {
                acc0[r] = fmaf(w0reg[0][r][0], x0,
                          fmaf(w0reg[0][r][1], x1,
                          fmaf(w0reg[0][r][2], x2, acc0[r])));
                acc1[r] = fmaf(w0reg[1][r][0], x0,
                          fmaf(w0reg[1][r][1], x1,
                          fmaf(w0reg[1][r][2], x2, acc1[r])));
            }
            if (t > 0) {
                int rb = (t - 1) * 512 + quad * 128 + e * 8;
                bf16x8 bh = *(const bf16x8*)&shi[rb];
                bf16x8 bl = *(const bf16x8*)&slo[rb];
                acc0 = __builtin_amdgcn_mfma_f32_16x16x32_bf16(whh_h0, bh, acc0, 0, 0, 0);
                acc0 = __builtin_amdgcn_mfma_f32_16x16x32_bf16(whh_h0, bl, acc0, 0, 0, 0);
                acc0 = __builtin_amdgcn_mfma_f32_16x16x32_bf16(whh_l0, bh, acc0, 0, 0, 0);
                acc1 = __builtin_amdgcn_mfma_f32_16x16x32_bf16(whh_h1, bh, acc1, 0, 0, 0);
                acc1 = __builtin_amdgcn_mfma_f32_16x16x32_bf16(whh_h1, bl, acc1, 0, 0, 0);
                acc1 = __builtin_amdgcn_mfma_f32_16x16x32_bf16(whh_l1, bh, acc1, 0, 0, 0);
            }
            ACT_STORE(t);
        }
    }

    // ================= layers 1..4 (both projections via MFMA) ===========
    for (int l = 1; l < 5; ++l) {
        const float* Wi = WihR + (l - 1) * 4096;
        const float* Wh = Whh + l * 4096;
        LOAD_FRAG(Wi, orow_t0, wih_h0, wih_l0);
        LOAD_FRAG(Wi, orow_t1, wih_h1, wih_l1);
        LOAD_FRAG(Wh, orow_t0, whh_h0, whh_l0);
        LOAD_FRAG(Wh, orow_t1, whh_h1, whh_l1);
        LOAD_BIAS(l);
        c0 = 0.f; c1 = 0.f;

        for (int t = 0; t < T_STEPS; ++t) {
            f32x4 acc0, acc1;
            {   // ih: x = h_{l-1}(t); bias rides in as C of first MFMA
                int rb = t * 512 + quad * 128 + e * 8;
                bf16x8 bh = *(const bf16x8*)&shi[rb];
                bf16x8 bl = *(const bf16x8*)&slo[rb];
                acc0 = __builtin_amdgcn_mfma_f32_16x16x32_bf16(wih_h0, bh, bias0v, 0, 0, 0);
                acc0 = __builtin_amdgcn_mfma_f32_16x16x32_bf16(wih_h0, bl, acc0, 0, 0, 0);
                acc0 = __builtin_amdgcn_mfma_f32_16x16x32_bf16(wih_l0, bh, acc0, 0, 0, 0);
                acc1 = __builtin_amdgcn_mfma_f32_16x16x32_bf16(wih_h1, bh, bias1v, 0, 0, 0);
                acc1 = __builtin_amdgcn_mfma_f32_16x16x32_bf16(wih_h1, bl, acc1, 0, 0, 0);
                acc1 = __builtin_amdgcn_mfma_f32_16x16x32_bf16(wih_l1, bh, acc1, 0, 0, 0);
            }
            if (t > 0) {
                int rb = (t - 1) * 512 + quad * 128 + e * 8;
                bf16x8 bh = *(const bf16x8*)&shi[rb];
                bf16x8 bl = *(const bf16x8*)&slo[rb];
                acc0 = __builtin_amdgcn_mfma_f32_16x16x32_bf16(whh_h0, bh, acc0, 0, 0, 0);
                acc0 = __builtin_amdgcn_mfma_f32_16x16x32_bf16(whh_h0, bl, acc0, 0, 0, 0);
                acc0 = __builtin_amdgcn_mfma_f32_16x16x32_bf16(whh_l0, bh, acc0, 0, 0, 0);
                acc1 = __builtin_amdgcn_mfma_f32_16x16x32_bf16(whh_h1, bh, acc1, 0, 0, 0);
                acc1 = __builtin_amdgcn_mfma_f32_16x16x32_bf16(whh_h1, bl, acc1, 0, 0, 0);
                acc1 = __builtin_amdgcn_mfma_f32_16x16x32_bf16(whh_l1, bh, acc1, 0, 0, 0);
            }
            ACT_STORE(t);
        }
    }
    __syncthreads();

    // ---- epilogue: raw copy of frag-layout hi/lo to global for fc ----
    {
        size_t base = ((size_t)(sensor * NGRP + blockIdx.x)) * (20 * 512);
        float4* dh = (float4*)(Xhi + base);
        float4* dl = (float4*)(Xlo + base);
        const float4* sh = (const float4*)shi;
        const float4* sl = (const float4*)slo;
        for (int i = tid; i < 20 * 512 / 8; i += 256) { dh[i] = sh[i]; dl[i] = sl[i]; }
    }
#undef LOAD_FRAG
#undef LOAD_BIAS
#undef ACT_STORE
}

// ---------------------------------------------------------------------------
// Fused fc1+ReLU+fc2. 512 blocks x 256 thr (4 waves). Block = 32 batch cols.
// wave = (kv K-half, mv m-half): kv picks sensor (ks = kv*20+kk), mv picks
// 4 of 8 m-tiles. A-frags (W1 hi/lo) are read exactly ONCE per block
// (336 MB total); B dup only x2 (164 MB). Single LDS K-reduce, no per-wave
// W1 replication (R6's 671 MB / R5's 2.7 GB).
__global__ __launch_bounds__(256, 2)
void fc_mfma(const __bf16* __restrict__ Xhi, const __bf16* __restrict__ Xlo,
             const __bf16* __restrict__ w1ah, const __bf16* __restrict__ w1al,
             const float* __restrict__ fc1_b, const float* __restrict__ fc2_w,
             const float* __restrict__ fc2_b, float* __restrict__ out) {
    const int tid  = threadIdx.x;
    const int wv   = tid >> 6;
    const int lane = tid & 63;
    const int e    = lane & 15;
    const int quad = lane >> 4;
    const int kv   = wv & 1;         // K half (== sensor)
    const int mv   = wv >> 1;        // m half (4 m-tiles)
    const int g0   = blockIdx.x * 2; // two 16-col groups

    __shared__ __align__(16) f32x4 sacc[2][4][2][64];   // [mv][m][cg][lane] 16KB
    __shared__ float sred[2][2][16][5];                 // [mv][cg][e][n]

    f32x4 acc[4][2];
#pragma unroll
    for (int m = 0; m < 4; ++m)
#pragma unroll
        for (int cg = 0; cg < 2; ++cg) acc[m][cg] = (f32x4){0.f, 0.f, 0.f, 0.f};

    for (int kk = 0; kk < 20; ++kk) {
        int ks = kv * 20 + kk;
        bf16x8 bh[2], bl[2];
#pragma unroll
        for (int cg = 0; cg < 2; ++cg) {
            size_t bb = ((size_t)(kv * NGRP + g0 + cg)) * (20 * 512) + kk * 512 + lane * 8;
            bh[cg] = *(const bf16x8*)(Xhi + bb);
            bl[cg] = *(const bf16x8*)(Xlo + bb);
        }
#pragma unroll
        for (int m = 0; m < 4; ++m) {
            int mt = mv * 4 + m;
            size_t ab = ((size_t)((mt * 40 + ks) * 64 + lane)) * 8;
            bf16x8 ah = *(const bf16x8*)(w1ah + ab);
            bf16x8 al = *(const bf16x8*)(w1al + ab);
#pragma unroll
            for (int cg = 0; cg < 2; ++cg) {
                acc[m][cg] = __builtin_amdgcn_mfma_f32_16x16x32_bf16(ah, bh[cg], acc[m][cg], 0, 0, 0);
                acc[m][cg] = __builtin_amdgcn_mfma_f32_16x16x32_bf16(ah, bl[cg], acc[m][cg], 0, 0, 0);
                acc[m][cg] = __builtin_amdgcn_mfma_f32_16x16x32_bf16(al, bh[cg], acc[m][cg], 0, 0, 0);
            }
        }
    }

    if (kv == 1) {
#pragma unroll
        for (int m = 0; m < 4; ++m)
#pragma unroll
            for (int cg = 0; cg < 2; ++cg) sacc[mv][m][cg][lane] = acc[m][cg];
    }
    __syncthreads();

    if (kv == 0) {
        float p[2][5];
#pragma unroll
        for (int cg = 0; cg < 2; ++cg)
#pragma unroll
            for (int n = 0; n < 5; ++n) p[cg][n] = 0.f;
#pragma unroll
        for (int m = 0; m < 4; ++m) {
            int mt = mv * 4 + m;
#pragma unroll
            for (int cg = 0; cg < 2; ++cg) {
                f32x4 z  = acc[m][cg];
                f32x4 zz = sacc[mv][m][cg][lane];
#pragma unroll
                for (int r = 0; r < 4; ++r) {
                    int row = mt * 16 + quad * 4 + r;   // C row = quad*4 + reg
                    float v = fmaxf(z[r] + zz[r] + fc1_b[row], 0.f);
#pragma unroll
                    for (int n = 0; n < 5; ++n)
                        p[cg][n] = fmaf(v, fc2_w[n * 128 + row], p[cg][n]);
                }
            }
        }
#pragma unroll
        for (int cg = 0; cg < 2; ++cg)
#pragma unroll
            for (int n = 0; n < 5; ++n) {
                p[cg][n] += __shfl_xor(p[cg][n], 16, 64);
                p[cg][n] += __shfl_xor(p[cg][n], 32, 64);
            }
        if (quad == 0) {
#pragma unroll
            for (int cg = 0; cg < 2; ++cg)
#pragma unroll
                for (int n = 0; n < 5; ++n) sred[mv][cg][e][n] = p[cg][n];
        }
    }
    __syncthreads();
    if (tid < 160) {
        int col = tid / 5, n = tid - col * 5;           // col 0..31
        out[((size_t)(blockIdx.x * 32 + col)) * 5 + n] =
            sred[0][col >> 4][col & 15][n] + sred[1][col >> 4][col & 15][n] + fc2_b[n];
    }
}

// ---------------------------------------------------------------------------
extern "C" void kernel_launch(void* const* d_in, const int* in_sizes, int n_in,
                              void* d_out, int out_size, void* d_ws, size_t ws_size,
                              hipStream_t stream) {
    const float* accel  = (const float*)d_in[0];
    const float* gyro   = (const float*)d_in[1];
    const float* aWih0  = (const float*)d_in[2];
    const float* aWihR  = (const float*)d_in[3];
    const float* aWhh   = (const float*)d_in[4];
    const float* aBih   = (const float*)d_in[5];
    const float* aBhh   = (const float*)d_in[6];
    const float* gWih0  = (const float*)d_in[7];
    const float* gWihR  = (const float*)d_in[8];
    const float* gWhh   = (const float*)d_in[9];
    const float* gBih   = (const float*)d_in[10];
    const float* gBhh   = (const float*)d_in[11];
    const float* fc1_w  = (const float*)d_in[12];
    const float* fc1_b  = (const float*)d_in[13];
    const float* fc2_w  = (const float*)d_in[14];
    const float* fc2_b  = (const float*)d_in[15];
    float* out = (float*)d_out;

    const size_t XN = (size_t)2 * NGRP * 20 * 512;    // 20,971,520 bf16 each
    __bf16* Xhi  = (__bf16*)d_ws;
    __bf16* Xlo  = Xhi + XN;
    __bf16* W1ah = Xlo + XN;                          // 163,840 bf16 each
    __bf16* W1al = W1ah + 163840;

    hipLaunchKernelGGL(lstm5_mfma, dim3(NGRP, 2), dim3(256), 0, stream,
                       accel, gyro, aWih0, aWihR, aWhh, aBih, aBhh,
                       gWih0, gWihR, gWhh, gBih, gBhh,
                       fc1_w, W1ah, W1al, Xhi, Xlo);

    hipLaunchKernelGGL(fc_mfma, dim3(B_TOTAL / 32), dim3(256), 0, stream,
                       Xhi, Xlo, W1ah, W1al, fc1_b, fc2_w, fc2_b, out);
}